// Round 16
// baseline (2564.388 us; speedup 1.0000x reference)
//
#include <hip/hip_runtime.h>
#include <hip/hip_fp16.h>
#include <math.h>

#define B   2
#define H   192
#define W   320
#define HW  (H * W)
#define BHW (B * HW)
#define CTX 195
#define CH  198   // 3 im + 195 ctx channels per side

// output offsets (in floats), concatenated in reference return order
#define OFS_CUR   0
#define OFS_REF0  (3 * BHW)
#define OFS_REF2  (6 * BHW)
#define OFS_CTX0  (9 * BHW)
#define OFS_CTX2  (9 * BHW + CTX * BHW)
#define OFS_OFF0  (9 * BHW + 2 * CTX * BHW)
#define OFS_OFF1  (OFS_OFF0 + 2 * BHW)

// transposed-path geometry
#define TSZ    ((size_t)2 * B * HW * CH)  // elements of T (fp16)
#define NTB    (2 * B * (HW / 64))        // 3840 transpose blocks
#define NSPB   ((2 * BHW + 255) / 256)    // 960 splat blocks
#define LDSW   199                        // transpose LDS row stride (odd)
#define NPXB   16                         // pixels per interp block
#define NTHR   256                        // interp block threads (4 waves)
#define NCHK   (HW / NPXB)                // 3840 chunks per (s,b) image
#define NBLK2  (2 * B * NCHK)             // 15360 interp blocks, div by 8

// fallback (R4) geometry
#define F_NCH   33
#define F_NGRP  6
#define F_TX    32
#define F_TY    8
#define F_NTX   (W / F_TX)
#define F_NTY   (H / F_TY)
#define F_NTILE (F_NTX * F_NTY * B)       // 480
#define F_NBLK  (F_NTILE * F_NGRP * 2)    // 5760

typedef float f4a __attribute__((ext_vector_type(4), aligned(4)));
typedef _Float16 h8 __attribute__((ext_vector_type(8), aligned(4)));

__device__ __forceinline__ int iclip(int v, int lo, int hi) {
    return v < lo ? lo : (v > hi ? hi : v);
}

// ---------------- fused splat + transpose ----------------
__global__ __launch_bounds__(256) void prep_kernel(
    const float* __restrict__ im0,  const float* __restrict__ im2,
    const float* __restrict__ ctx0, const float* __restrict__ ctx2,
    const float* __restrict__ flow0, const float* __restrict__ flow1,
    const float* __restrict__ dep0,  const float* __restrict__ dep1,
    _Float16* __restrict__ T, float* __restrict__ acc4)
{
    __shared__ float lds[64 * LDSW];

    if ((int)blockIdx.x < NTB) {
        int lin   = blockIdx.x;
        int chunk = lin % (HW / 64);
        int rest  = lin / (HW / 64);
        int b = rest % B;
        int s = rest / B;
        int pix0 = chunk * 64;

        const float* im  = s ? im2  : im0;
        const float* ctx = s ? ctx2 : ctx0;

        for (int j = (int)threadIdx.x; j < CH * 64; j += 256) {
            int c = j >> 6;
            int p = j & 63;
            const float* src = (c < 3) ? im + (b * 3 + c) * HW
                                       : ctx + (b * CTX + (c - 3)) * HW;
            lds[p * LDSW + c] = src[pix0 + p];
        }
        __syncthreads();
        _Float16* Tb = T + ((size_t)((s * B + b) * HW + pix0)) * CH;
        for (int j = (int)threadIdx.x; j < CH * 64; j += 256) {
            int p = j / CH;
            int c = j - p * CH;
            Tb[(size_t)p * CH + c] = (_Float16)lds[p * LDSW + c];
        }
    } else {
        int tid = ((int)blockIdx.x - NTB) * 256 + (int)threadIdx.x;
        if (tid >= 2 * BHW) return;
        int s   = tid / BHW;
        int p   = tid - s * BHW;
        int b   = p / HW;
        int pix = p - b * HW;
        int y   = pix / W;
        int x   = pix - y * W;

        const float* flow = s ? flow1 : flow0;
        const float* dep  = s ? dep1  : dep0;
        float fx = flow[(b * 2 + 0) * HW + pix];
        float fy = flow[(b * 2 + 1) * HW + pix];
        float d  = dep[b * HW + pix];

        int xL = (int)floorf((float)x + fx);
        int yT = (int)floorf((float)y + fy);

        float* ab = acc4 + (size_t)(s * B + b) * HW * 4;
        float wx = -fx * d;
        float wy = -fy * d;
        #pragma unroll
        for (int dy = 0; dy < 2; dy++) {
            #pragma unroll
            for (int dx = 0; dx < 2; dx++) {
                int xi = xL + dx;
                int yi = yT + dy;
                if (xi >= 0 && xi < W && yi >= 0 && yi < H) {
                    float* q = ab + (size_t)(yi * W + xi) * 4;
                    atomicAdd(q + 0, wx);
                    atomicAdd(q + 1, wy);
                    atomicAdd(q + 2, d);
                }
            }
        }
    }
}

__global__ __launch_bounds__(256) void norm_kernel(
    float* __restrict__ out, const float* __restrict__ acc4)
{
    int tid = blockIdx.x * blockDim.x + threadIdx.x;
    if (tid >= 2 * BHW) return;
    int s   = tid / BHW;
    int p   = tid - s * BHW;
    int b   = p / HW;
    int pix = p - b * HW;

    const float* q = acc4 + ((size_t)(s * B + b) * HW + pix) * 4;
    float ax = q[0], ay = q[1], c = q[2];
    float* acc = out + (s ? OFS_OFF1 : OFS_OFF0) + b * 2 * HW;
    if (c > 0.0f) {
        acc[pix]      = ax / c;
        acc[HW + pix] = ay / c;
    } else {
        acc[pix]      = 0.0f;
        acc[HW + pix] = 0.0f;
    }
}

__global__ __launch_bounds__(256) void cur_kernel(float* __restrict__ out)
{
    int i = blockIdx.x * blockDim.x + threadIdx.x;
    if (i < 3 * BHW)
        out[OFS_CUR + i] = 0.5f * (out[OFS_REF0 + i] + out[OFS_REF2 + i]);
}

// ---------------- transposed-gather interp ----------------
// 16 px/block, 4 waves; per-pixel 5x5 merged weights via tap-scatter (exact
// clamp semantics); clamped row/col offsets keep all reads in-image;
// h8 gathers, 2 px per wave-load, 8 ch per lane. pr loop NOT unrolled so only
// one pixel's state is live -> fits 64 VGPR without spills at 8 waves/EU.
__global__ __launch_bounds__(NTHR, 8) void interp_t_kernel(
    const _Float16* __restrict__ T,
    const float* __restrict__ filt0, const float* __restrict__ filt1,
    float* __restrict__ out)
{
    __shared__ float fwl[NPXB * 17];    // [p][tap]
    __shared__ float mwl[NPXB * 25];    // [p][r*5+c] merged weights
    __shared__ float geoA[NPXB * 4];    // a00,a10,a01,a11 (0 if invalid)
    __shared__ int   geoC[NPXB * 4];    // xL, yT, bx, by (sanitized)
    __shared__ int   rofs[NPXB * 5];    // clamped row offsets (elements)
    __shared__ int   cofs[NPXB * 5];    // clamped col offsets (elements)
    __shared__ float outb[NPXB * 199];  // [p][c]

    int lin = blockIdx.x;
    int newlin = (lin & 7) * (NBLK2 / 8) + (lin >> 3);   // XCD swizzle
    int chunk = newlin % NCHK;
    int rest  = newlin / NCHK;
    int b = rest % B;
    int s = rest / B;
    int px0 = chunk * NPXB;      // 16 consecutive px within one row
    int y0  = px0 / W;
    int x0  = px0 - y0 * W;

    const float* off  = out + (s ? OFS_OFF1 : OFS_OFF0) + b * 2 * HW;
    const float* filt = (s ? filt1 : filt0) + b * 16 * HW;
    const _Float16* Tb = T + (size_t)(s * B + b) * HW * CH;

    int t = (int)threadIdx.x;

    // zero merged weights
    for (int idx = t; idx < 25 * NPXB; idx += NTHR) mwl[idx] = 0.0f;
    // cooperative filt load (one element per thread: 16 taps x 16 px = 256)
    {
        int tap = t >> 4, p = t & 15;
        fwl[p * 17 + tap] = filt[tap * HW + px0 + p];
    }
    // per-pixel geometry
    if (t < NPXB) {
        int p = t;
        float ox = off[px0 + p];
        float oy = off[HW + px0 + p];
        float x2 = (float)(x0 + p) + ox;
        float y2 = (float)y0 + oy;
        bool valid = (x2 >= 0.0f) && (x2 <= (float)(W - 1)) &&
                     (y2 >= 0.0f) && (y2 <= (float)(H - 1));
        float xLf = floorf(x2), yTf = floorf(y2);
        float al = x2 - xLf, be = y2 - yTf;
        int xL = valid ? (int)xLf : 1;
        int yT = valid ? (int)yTf : 1;
        geoA[p * 4 + 0] = valid ? (1.0f - al) * (1.0f - be) : 0.0f;
        geoA[p * 4 + 1] = valid ? al * (1.0f - be) : 0.0f;
        geoA[p * 4 + 2] = valid ? (1.0f - al) * be : 0.0f;
        geoA[p * 4 + 3] = valid ? al * be : 0.0f;
        geoC[p * 4 + 0] = xL;
        geoC[p * 4 + 1] = yT;
        geoC[p * 4 + 2] = xL - 1 > 0 ? xL - 1 : 0;   // bx
        geoC[p * 4 + 3] = yT - 1 > 0 ? yT - 1 : 0;   // by
    }
    __syncthreads();

    // clamped row/col element offsets (weight-nonzero cells never clamp)
    if (t < 2 * 5 * NPXB) {
        if (t < 5 * NPXB) {
            int p = t / 5, r = t - p * 5;
            int by = geoC[p * 4 + 3];
            int yr = by + r; if (yr > H - 1) yr = H - 1;
            rofs[p * 5 + r] = yr * (W * CH);
        } else {
            int j = t - 5 * NPXB;
            int p = j / 5, c = j - p * 5;
            int bx = geoC[p * 4 + 2];
            int xc = bx + c; if (xc > W - 1) xc = W - 1;
            cofs[p * 5 + c] = xc * CH;
        }
    }

    // tap-scatter: one thread per (pixel, tap); exact per-corner clamping
    {
        int p = t >> 4, tap = t & 15;
        int fi = tap & 3, fj = tap >> 2;
        int xL = geoC[p * 4 + 0], yT = geoC[p * 4 + 1];
        int bx = geoC[p * 4 + 2], by = geoC[p * 4 + 3];
        float fw = fwl[p * 17 + tap];
        float a00 = geoA[p * 4 + 0], a10 = geoA[p * 4 + 1];
        float a01 = geoA[p * 4 + 2], a11 = geoA[p * 4 + 3];
        int xi  = iclip(xL + fi - 1, 0, W - 1);
        int xi1 = xi + 1 > W - 1 ? W - 1 : xi + 1;
        int yi  = iclip(yT + fj - 1, 0, H - 1);
        int yi1 = yi + 1 > H - 1 ? H - 1 : yi + 1;
        float* mwp = &mwl[p * 25];
        atomicAdd(&mwp[(yi  - by) * 5 + (xi  - bx)], fw * a00);
        atomicAdd(&mwp[(yi  - by) * 5 + (xi1 - bx)], fw * a10);
        atomicAdd(&mwp[(yi1 - by) * 5 + (xi  - bx)], fw * a01);
        atomicAdd(&mwp[(yi1 - by) * 5 + (xi1 - bx)], fw * a11);
    }
    __syncthreads();

    // branch-free gather: 2 pixels per wave-load, 8 ch per lane.
    // pr loop deliberately NOT unrolled: one pixel's acc/load state live.
    int wave = t >> 6, lane = t & 63;    // wave in [0,4)
    int grp = lane >> 5;                 // 0: px A, 1: px B
    int li  = lane & 31;
    int lcl = li < 24 ? li : 24;
    int ch0 = lcl * 8;                   // channels ch0..ch0+7 (lane 24: 6 valid)

    #pragma unroll 1
    for (int pr = 0; pr < 2; pr++) {
        int p = wave * 4 + pr * 2 + grp; // 4 waves x 4 px = 16 px
        const float* mwp = &mwl[p * 25];
        const int* rp = &rofs[p * 5];
        const int* cp = &cofs[p * 5];
        const _Float16* bp = Tb + ch0;
        float a0 = 0, a1 = 0, a2 = 0, a3 = 0, a4 = 0, a5 = 0, a6 = 0, a7 = 0;
        #pragma unroll
        for (int r = 0; r < 5; r++) {
            const _Float16* rowp = bp + rp[r];
            #pragma unroll
            for (int c = 0; c < 5; c++) {
                h8 v = *(const h8*)(rowp + cp[c]);
                float w = mwp[r * 5 + c];
                a0 = fmaf(w, (float)v[0], a0);
                a1 = fmaf(w, (float)v[1], a1);
                a2 = fmaf(w, (float)v[2], a2);
                a3 = fmaf(w, (float)v[3], a3);
                a4 = fmaf(w, (float)v[4], a4);
                a5 = fmaf(w, (float)v[5], a5);
                a6 = fmaf(w, (float)v[6], a6);
                a7 = fmaf(w, (float)v[7], a7);
            }
        }
        float* ob = &outb[p * 199 + ch0];
        if (li < 24) {
            ob[0] = a0; ob[1] = a1; ob[2] = a2; ob[3] = a3;
            ob[4] = a4; ob[5] = a5; ob[6] = a6; ob[7] = a7;
        } else if (li == 24) {
            ob[0] = a0; ob[1] = a1; ob[2] = a2;
            ob[3] = a3; ob[4] = a4; ob[5] = a5;
        }
    }

    __syncthreads();
    // coalesced plane writes
    for (int idx = t; idx < CH * NPXB; idx += NTHR) {
        int c = idx >> 4;
        int p = idx & 15;
        float v = outb[p * 199 + c];
        if (c < 3)
            out[(s ? OFS_REF2 : OFS_REF0) + (b * 3 + c) * HW + px0 + p] = v;
        else
            __builtin_nontemporal_store(
                v, &out[(s ? OFS_CTX2 : OFS_CTX0) + (b * CTX + (c - 3)) * HW + px0 + p]);
    }
}

// ---------------- fallback path (R4 interp, fp32 planes) ----------------

#define VBODY(PLANE, STORE)                                            \
    {                                                                  \
        const float* p0 = (PLANE) + base;                              \
        float acc = 0.0f;                                              \
        _Pragma("unroll")                                              \
        for (int r = 0; r < 5; r++) {                                  \
            const float* row = p0 + r * W;                             \
            f4a v0 = *(const f4a*)row;                                 \
            float v4 = row[4];                                         \
            acc = fmaf(mw[r][0], v0.x, acc);                           \
            acc = fmaf(mw[r][1], v0.y, acc);                           \
            acc = fmaf(mw[r][2], v0.z, acc);                           \
            acc = fmaf(mw[r][3], v0.w, acc);                           \
            acc = fmaf(mw[r][4], v4,   acc);                           \
        }                                                              \
        STORE;                                                         \
    }

#define BBODY(PLANE, STORE)                                            \
    {                                                                  \
        const float* plane = (PLANE);                                  \
        float acc = 0.0f;                                              \
        _Pragma("unroll")                                              \
        for (int fj = 0; fj < 4; fj++) {                               \
            const float* rT = plane + yi[fj]  * W;                     \
            const float* rB = plane + yi1[fj] * W;                     \
            _Pragma("unroll")                                          \
            for (int fi = 0; fi < 4; fi++) {                           \
                float samp = a00 * rT[xi[fi]] + a10 * rT[xi1[fi]]      \
                           + a01 * rB[xi[fi]] + a11 * rB[xi1[fi]];     \
                acc = fmaf(fw[fj * 4 + fi], samp, acc);                \
            }                                                          \
        }                                                              \
        STORE;                                                         \
    }

__global__ __launch_bounds__(256) void interp_f_kernel(
    const float* __restrict__ im0,   const float* __restrict__ im2,
    const float* __restrict__ ctx0,  const float* __restrict__ ctx2,
    const float* __restrict__ filt0, const float* __restrict__ filt1,
    float* __restrict__ out)
{
    int lin = blockIdx.x + F_NTILE * (blockIdx.y + F_NGRP * blockIdx.z);
    int newlin = (lin & 7) * (F_NBLK / 8) + (lin >> 3);
    int tile = newlin % F_NTILE;
    int rest = newlin / F_NTILE;
    int g = rest % F_NGRP;
    int s = rest / F_NGRP;
    int b  = tile / (F_NTX * F_NTY);
    int t2 = tile % (F_NTX * F_NTY);
    int x = (t2 % F_NTX) * F_TX + ((int)threadIdx.x % F_TX);
    int y = (t2 / F_NTX) * F_TY + ((int)threadIdx.x / F_TX);
    int pix = y * W + x;

    const float* off = out + (s ? OFS_OFF1 : OFS_OFF0) + b * 2 * HW;
    float ox = off[pix];
    float oy = off[HW + pix];
    float x2 = (float)x + ox;
    float y2 = (float)y + oy;

    bool valid = (x2 >= 0.0f) && (x2 <= (float)(W - 1)) &&
                 (y2 >= 0.0f) && (y2 <= (float)(H - 1));

    const float* imsrc  = s ? im2  : im0;
    const float* ctxsrc = s ? ctx2 : ctx0;
    float* oim  = out + (s ? OFS_REF2 : OFS_REF0) + b * 3 * HW + pix;
    float* octx = out + (s ? OFS_CTX2 : OFS_CTX0) + b * CTX * HW + pix;

    int c0 = g * F_NCH, c1 = c0 + F_NCH;
    int imEnd  = c1 < 3 ? c1 : 3;
    int ctxBeg = c0 > 3 ? c0 : 3;

    if (!valid) {
        for (int c = c0; c < imEnd; c++) oim[c * HW] = 0.0f;
        for (int c = ctxBeg; c < c1; c++)
            __builtin_nontemporal_store(0.0f, &octx[(c - 3) * HW]);
        return;
    }

    float xLf = floorf(x2), yTf = floorf(y2);
    float alpha = x2 - xLf, beta = y2 - yTf;
    int xL = (int)xLf, yT = (int)yTf;

    const float* filt = (s ? filt1 : filt0) + b * 16 * HW + pix;
    float fw[16];
    #pragma unroll
    for (int t = 0; t < 16; t++) fw[t] = filt[t * HW];

    float a00 = (1.0f - alpha) * (1.0f - beta);
    float a10 = alpha * (1.0f - beta);
    float a01 = (1.0f - alpha) * beta;
    float a11 = alpha * beta;

    bool interior = (xL >= 1) && (xL <= W - 4) && (yT >= 1) && (yT <= H - 4);

    if (interior) {
        float mw[5][5];
        #pragma unroll
        for (int r = 0; r < 5; r++) {
            #pragma unroll
            for (int c = 0; c < 5; c++) {
                float v = 0.0f;
                if (r < 4 && c < 4)   v += a00 * fw[r * 4 + c];
                if (r < 4 && c >= 1)  v += a10 * fw[r * 4 + c - 1];
                if (r >= 1 && c < 4)  v += a01 * fw[(r - 1) * 4 + c];
                if (r >= 1 && c >= 1) v += a11 * fw[(r - 1) * 4 + c - 1];
                mw[r][c] = v;
            }
        }
        int base = (yT - 1) * W + (xL - 1);
        for (int c = c0; c < imEnd; c++)
            VBODY(imsrc + (b * 3 + c) * HW, oim[c * HW] = acc)
        #pragma unroll 2
        for (int c = ctxBeg; c < c1; c++)
            VBODY(ctxsrc + (b * CTX + (c - 3)) * HW,
                  __builtin_nontemporal_store(acc, &octx[(c - 3) * HW]))
    } else {
        int xi[4], xi1[4], yi[4], yi1[4];
        #pragma unroll
        for (int f = 0; f < 4; f++) {
            int a = iclip(xL + f - 1, 0, W - 1);
            xi[f]  = a;
            xi1[f] = a + 1 > W - 1 ? W - 1 : a + 1;
            int bb = iclip(yT + f - 1, 0, H - 1);
            yi[f]  = bb;
            yi1[f] = bb + 1 > H - 1 ? H - 1 : bb + 1;
        }
        for (int c = c0; c < imEnd; c++)
            BBODY(imsrc + (b * 3 + c) * HW, oim[c * HW] = acc)
        for (int c = ctxBeg; c < c1; c++)
            BBODY(ctxsrc + (b * CTX + (c - 3)) * HW,
                  __builtin_nontemporal_store(acc, &octx[(c - 3) * HW]))
    }
}

// ---------------- launch ----------------

extern "C" void kernel_launch(void* const* d_in, const int* in_sizes, int n_in,
                              void* d_out, int out_size, void* d_ws, size_t ws_size,
                              hipStream_t stream)
{
    const float* im0    = (const float*)d_in[0];
    const float* im2    = (const float*)d_in[1];
    const float* ctx0   = (const float*)d_in[2];
    const float* ctx2   = (const float*)d_in[3];
    const float* flow01 = (const float*)d_in[4];
    const float* flow10 = (const float*)d_in[5];
    const float* dep0   = (const float*)d_in[6];
    const float* dep1   = (const float*)d_in[7];
    const float* filt0  = (const float*)d_in[8];
    const float* filt1  = (const float*)d_in[9];

    float* out = (float*)d_out;

    // ws layout: T (TSZ halfs) first, then acc4 (2*BHW*4 floats).
    size_t t_bytes    = TSZ * sizeof(_Float16);
    size_t acc4_bytes = (size_t)2 * BHW * 4 * sizeof(float);
    size_t need = t_bytes + acc4_bytes;
    bool use_t = ws_size >= need;

    _Float16* T = (_Float16*)d_ws;
    float* acc4 = use_t ? (float*)((char*)d_ws + t_bytes) : (float*)d_ws;

    hipMemsetAsync(acc4, 0, acc4_bytes, stream);

    dim3 blk(256);
    if (use_t) {
        prep_kernel<<<dim3(NTB + NSPB), blk, 0, stream>>>(
            im0, im2, ctx0, ctx2, flow01, flow10, dep0, dep1, T, acc4);
        norm_kernel<<<dim3((2 * BHW + 255) / 256), blk, 0, stream>>>(out, acc4);
        interp_t_kernel<<<dim3(NBLK2), dim3(NTHR), 0, stream>>>(T, filt0, filt1, out);
    } else {
        prep_kernel<<<dim3(NTB + NSPB), blk, 0, stream>>>(
            im0, im2, ctx0, ctx2, flow01, flow10, dep0, dep1,
            (_Float16*)d_ws, acc4);
        norm_kernel<<<dim3((2 * BHW + 255) / 256), blk, 0, stream>>>(out, acc4);
        dim3 igrid(F_NTILE, F_NGRP, 2);
        interp_f_kernel<<<igrid, blk, 0, stream>>>(
            im0, im2, ctx0, ctx2, filt0, filt1, out);
    }

    cur_kernel<<<dim3((3 * BHW + 255) / 256), blk, 0, stream>>>(out);
}

// Round 17
// 428.074 us; speedup vs baseline: 5.9905x; 5.9905x over previous
//
#include <hip/hip_runtime.h>
#include <hip/hip_fp16.h>
#include <math.h>

#define B   2
#define H   192
#define W   320
#define HW  (H * W)
#define BHW (B * HW)
#define CTX 195
#define CH  198   // 3 im + 195 ctx channels per side

// output offsets (in floats), concatenated in reference return order
#define OFS_CUR   0
#define OFS_REF0  (3 * BHW)
#define OFS_REF2  (6 * BHW)
#define OFS_CTX0  (9 * BHW)
#define OFS_CTX2  (9 * BHW + CTX * BHW)
#define OFS_OFF0  (9 * BHW + 2 * CTX * BHW)
#define OFS_OFF1  (OFS_OFF0 + 2 * BHW)

// transposed-path geometry
#define TSZ    ((size_t)2 * B * HW * CH)  // elements of T (fp16)
#define NTB    (2 * B * (HW / 64))        // 3840 transpose blocks
#define NSPB   ((2 * BHW + 255) / 256)    // 960 splat blocks
#define LDSW   199                        // transpose LDS row stride (odd)
#define NPXB   16                         // pixels per interp block
#define NTHR   256                        // interp block threads (4 waves)
#define NCHK   (HW / NPXB)                // 3840 chunks per (s,b) image
#define NBLK2  (2 * B * NCHK)             // 15360 interp blocks, div by 8

// fallback (R4) geometry
#define F_NCH   33
#define F_NGRP  6
#define F_TX    32
#define F_TY    8
#define F_NTX   (W / F_TX)
#define F_NTY   (H / F_TY)
#define F_NTILE (F_NTX * F_NTY * B)       // 480
#define F_NBLK  (F_NTILE * F_NGRP * 2)    // 5760

typedef float f4a __attribute__((ext_vector_type(4), aligned(4)));
typedef _Float16 h8 __attribute__((ext_vector_type(8), aligned(4)));

__device__ __forceinline__ int iclip(int v, int lo, int hi) {
    return v < lo ? lo : (v > hi ? hi : v);
}

// ---------------- fused splat + transpose ----------------
__global__ __launch_bounds__(256) void prep_kernel(
    const float* __restrict__ im0,  const float* __restrict__ im2,
    const float* __restrict__ ctx0, const float* __restrict__ ctx2,
    const float* __restrict__ flow0, const float* __restrict__ flow1,
    const float* __restrict__ dep0,  const float* __restrict__ dep1,
    _Float16* __restrict__ T, float* __restrict__ acc4)
{
    __shared__ float lds[64 * LDSW];

    if ((int)blockIdx.x < NTB) {
        int lin   = blockIdx.x;
        int chunk = lin % (HW / 64);
        int rest  = lin / (HW / 64);
        int b = rest % B;
        int s = rest / B;
        int pix0 = chunk * 64;

        const float* im  = s ? im2  : im0;
        const float* ctx = s ? ctx2 : ctx0;

        for (int j = (int)threadIdx.x; j < CH * 64; j += 256) {
            int c = j >> 6;
            int p = j & 63;
            const float* src = (c < 3) ? im + (b * 3 + c) * HW
                                       : ctx + (b * CTX + (c - 3)) * HW;
            lds[p * LDSW + c] = src[pix0 + p];
        }
        __syncthreads();
        _Float16* Tb = T + ((size_t)((s * B + b) * HW + pix0)) * CH;
        for (int j = (int)threadIdx.x; j < CH * 64; j += 256) {
            int p = j / CH;
            int c = j - p * CH;
            Tb[(size_t)p * CH + c] = (_Float16)lds[p * LDSW + c];
        }
    } else {
        int tid = ((int)blockIdx.x - NTB) * 256 + (int)threadIdx.x;
        if (tid >= 2 * BHW) return;
        int s   = tid / BHW;
        int p   = tid - s * BHW;
        int b   = p / HW;
        int pix = p - b * HW;
        int y   = pix / W;
        int x   = pix - y * W;

        const float* flow = s ? flow1 : flow0;
        const float* dep  = s ? dep1  : dep0;
        float fx = flow[(b * 2 + 0) * HW + pix];
        float fy = flow[(b * 2 + 1) * HW + pix];
        float d  = dep[b * HW + pix];

        int xL = (int)floorf((float)x + fx);
        int yT = (int)floorf((float)y + fy);

        float* ab = acc4 + (size_t)(s * B + b) * HW * 4;
        float wx = -fx * d;
        float wy = -fy * d;
        #pragma unroll
        for (int dy = 0; dy < 2; dy++) {
            #pragma unroll
            for (int dx = 0; dx < 2; dx++) {
                int xi = xL + dx;
                int yi = yT + dy;
                if (xi >= 0 && xi < W && yi >= 0 && yi < H) {
                    float* q = ab + (size_t)(yi * W + xi) * 4;
                    atomicAdd(q + 0, wx);
                    atomicAdd(q + 1, wy);
                    atomicAdd(q + 2, d);
                }
            }
        }
    }
}

__global__ __launch_bounds__(256) void norm_kernel(
    float* __restrict__ out, const float* __restrict__ acc4)
{
    int tid = blockIdx.x * blockDim.x + threadIdx.x;
    if (tid >= 2 * BHW) return;
    int s   = tid / BHW;
    int p   = tid - s * BHW;
    int b   = p / HW;
    int pix = p - b * HW;

    const float* q = acc4 + ((size_t)(s * B + b) * HW + pix) * 4;
    float ax = q[0], ay = q[1], c = q[2];
    float* acc = out + (s ? OFS_OFF1 : OFS_OFF0) + b * 2 * HW;
    if (c > 0.0f) {
        acc[pix]      = ax / c;
        acc[HW + pix] = ay / c;
    } else {
        acc[pix]      = 0.0f;
        acc[HW + pix] = 0.0f;
    }
}

__global__ __launch_bounds__(256) void cur_kernel(float* __restrict__ out)
{
    int i = blockIdx.x * blockDim.x + threadIdx.x;
    if (i < 3 * BHW)
        out[OFS_CUR + i] = 0.5f * (out[OFS_REF0 + i] + out[OFS_REF2 + i]);
}

// ---------------- transposed-gather interp ----------------
// 16 px/block, 4 waves; per-pixel 5x5 merged weights via tap-scatter (exact
// clamp semantics); clamped row/col offsets keep all reads in-image;
// h8 gathers, 2 px per wave-load, 8 ch per lane. pr loop NOT unrolled so only
// one pixel's state is live -> natural VGPR demand under the 64-reg cliff.
// NO min-waves launch bound (it forces VGPR=32 + spills on this compiler).
__global__ __launch_bounds__(NTHR) void interp_t_kernel(
    const _Float16* __restrict__ T,
    const float* __restrict__ filt0, const float* __restrict__ filt1,
    float* __restrict__ out)
{
    __shared__ float fwl[NPXB * 17];    // [p][tap]
    __shared__ float mwl[NPXB * 25];    // [p][r*5+c] merged weights
    __shared__ float geoA[NPXB * 4];    // a00,a10,a01,a11 (0 if invalid)
    __shared__ int   geoC[NPXB * 4];    // xL, yT, bx, by (sanitized)
    __shared__ int   rofs[NPXB * 5];    // clamped row offsets (elements)
    __shared__ int   cofs[NPXB * 5];    // clamped col offsets (elements)
    __shared__ float outb[NPXB * 199];  // [p][c]

    int lin = blockIdx.x;
    int newlin = (lin & 7) * (NBLK2 / 8) + (lin >> 3);   // XCD swizzle
    int chunk = newlin % NCHK;
    int rest  = newlin / NCHK;
    int b = rest % B;
    int s = rest / B;
    int px0 = chunk * NPXB;      // 16 consecutive px within one row
    int y0  = px0 / W;
    int x0  = px0 - y0 * W;

    const float* off  = out + (s ? OFS_OFF1 : OFS_OFF0) + b * 2 * HW;
    const float* filt = (s ? filt1 : filt0) + b * 16 * HW;
    const _Float16* Tb = T + (size_t)(s * B + b) * HW * CH;

    int t = (int)threadIdx.x;

    // zero merged weights
    for (int idx = t; idx < 25 * NPXB; idx += NTHR) mwl[idx] = 0.0f;
    // cooperative filt load (one element per thread: 16 taps x 16 px = 256)
    {
        int tap = t >> 4, p = t & 15;
        fwl[p * 17 + tap] = filt[tap * HW + px0 + p];
    }
    // per-pixel geometry
    if (t < NPXB) {
        int p = t;
        float ox = off[px0 + p];
        float oy = off[HW + px0 + p];
        float x2 = (float)(x0 + p) + ox;
        float y2 = (float)y0 + oy;
        bool valid = (x2 >= 0.0f) && (x2 <= (float)(W - 1)) &&
                     (y2 >= 0.0f) && (y2 <= (float)(H - 1));
        float xLf = floorf(x2), yTf = floorf(y2);
        float al = x2 - xLf, be = y2 - yTf;
        int xL = valid ? (int)xLf : 1;
        int yT = valid ? (int)yTf : 1;
        geoA[p * 4 + 0] = valid ? (1.0f - al) * (1.0f - be) : 0.0f;
        geoA[p * 4 + 1] = valid ? al * (1.0f - be) : 0.0f;
        geoA[p * 4 + 2] = valid ? (1.0f - al) * be : 0.0f;
        geoA[p * 4 + 3] = valid ? al * be : 0.0f;
        geoC[p * 4 + 0] = xL;
        geoC[p * 4 + 1] = yT;
        geoC[p * 4 + 2] = xL - 1 > 0 ? xL - 1 : 0;   // bx
        geoC[p * 4 + 3] = yT - 1 > 0 ? yT - 1 : 0;   // by
    }
    __syncthreads();

    // clamped row/col element offsets (weight-nonzero cells never clamp)
    if (t < 2 * 5 * NPXB) {
        if (t < 5 * NPXB) {
            int p = t / 5, r = t - p * 5;
            int by = geoC[p * 4 + 3];
            int yr = by + r; if (yr > H - 1) yr = H - 1;
            rofs[p * 5 + r] = yr * (W * CH);
        } else {
            int j = t - 5 * NPXB;
            int p = j / 5, c = j - p * 5;
            int bx = geoC[p * 4 + 2];
            int xc = bx + c; if (xc > W - 1) xc = W - 1;
            cofs[p * 5 + c] = xc * CH;
        }
    }

    // tap-scatter: one thread per (pixel, tap); exact per-corner clamping
    {
        int p = t >> 4, tap = t & 15;
        int fi = tap & 3, fj = tap >> 2;
        int xL = geoC[p * 4 + 0], yT = geoC[p * 4 + 1];
        int bx = geoC[p * 4 + 2], by = geoC[p * 4 + 3];
        float fw = fwl[p * 17 + tap];
        float a00 = geoA[p * 4 + 0], a10 = geoA[p * 4 + 1];
        float a01 = geoA[p * 4 + 2], a11 = geoA[p * 4 + 3];
        int xi  = iclip(xL + fi - 1, 0, W - 1);
        int xi1 = xi + 1 > W - 1 ? W - 1 : xi + 1;
        int yi  = iclip(yT + fj - 1, 0, H - 1);
        int yi1 = yi + 1 > H - 1 ? H - 1 : yi + 1;
        float* mwp = &mwl[p * 25];
        atomicAdd(&mwp[(yi  - by) * 5 + (xi  - bx)], fw * a00);
        atomicAdd(&mwp[(yi  - by) * 5 + (xi1 - bx)], fw * a10);
        atomicAdd(&mwp[(yi1 - by) * 5 + (xi  - bx)], fw * a01);
        atomicAdd(&mwp[(yi1 - by) * 5 + (xi1 - bx)], fw * a11);
    }
    __syncthreads();

    // branch-free gather: 2 pixels per wave-load, 8 ch per lane.
    // pr loop NOT unrolled: one pixel's acc/load state live at a time.
    int wave = t >> 6, lane = t & 63;    // wave in [0,4)
    int grp = lane >> 5;                 // 0: px A, 1: px B
    int li  = lane & 31;
    int lcl = li < 24 ? li : 24;
    int ch0 = lcl * 8;                   // channels ch0..ch0+7 (lane 24: 6 valid)

    #pragma unroll 1
    for (int pr = 0; pr < 2; pr++) {
        int p = wave * 4 + pr * 2 + grp; // 4 waves x 4 px = 16 px
        const float* mwp = &mwl[p * 25];
        const int* rp = &rofs[p * 5];
        const int* cp = &cofs[p * 5];
        const _Float16* bp = Tb + ch0;
        float a0 = 0, a1 = 0, a2 = 0, a3 = 0, a4 = 0, a5 = 0, a6 = 0, a7 = 0;
        #pragma unroll
        for (int r = 0; r < 5; r++) {
            const _Float16* rowp = bp + rp[r];
            #pragma unroll
            for (int c = 0; c < 5; c++) {
                h8 v = *(const h8*)(rowp + cp[c]);
                float w = mwp[r * 5 + c];
                a0 = fmaf(w, (float)v[0], a0);
                a1 = fmaf(w, (float)v[1], a1);
                a2 = fmaf(w, (float)v[2], a2);
                a3 = fmaf(w, (float)v[3], a3);
                a4 = fmaf(w, (float)v[4], a4);
                a5 = fmaf(w, (float)v[5], a5);
                a6 = fmaf(w, (float)v[6], a6);
                a7 = fmaf(w, (float)v[7], a7);
            }
        }
        float* ob = &outb[p * 199 + ch0];
        if (li < 24) {
            ob[0] = a0; ob[1] = a1; ob[2] = a2; ob[3] = a3;
            ob[4] = a4; ob[5] = a5; ob[6] = a6; ob[7] = a7;
        } else if (li == 24) {
            ob[0] = a0; ob[1] = a1; ob[2] = a2;
            ob[3] = a3; ob[4] = a4; ob[5] = a5;
        }
    }

    __syncthreads();
    // coalesced plane writes
    for (int idx = t; idx < CH * NPXB; idx += NTHR) {
        int c = idx >> 4;
        int p = idx & 15;
        float v = outb[p * 199 + c];
        if (c < 3)
            out[(s ? OFS_REF2 : OFS_REF0) + (b * 3 + c) * HW + px0 + p] = v;
        else
            __builtin_nontemporal_store(
                v, &out[(s ? OFS_CTX2 : OFS_CTX0) + (b * CTX + (c - 3)) * HW + px0 + p]);
    }
}

// ---------------- fallback path (R4 interp, fp32 planes) ----------------

#define VBODY(PLANE, STORE)                                            \
    {                                                                  \
        const float* p0 = (PLANE) + base;                              \
        float acc = 0.0f;                                              \
        _Pragma("unroll")                                              \
        for (int r = 0; r < 5; r++) {                                  \
            const float* row = p0 + r * W;                             \
            f4a v0 = *(const f4a*)row;                                 \
            float v4 = row[4];                                         \
            acc = fmaf(mw[r][0], v0.x, acc);                           \
            acc = fmaf(mw[r][1], v0.y, acc);                           \
            acc = fmaf(mw[r][2], v0.z, acc);                           \
            acc = fmaf(mw[r][3], v0.w, acc);                           \
            acc = fmaf(mw[r][4], v4,   acc);                           \
        }                                                              \
        STORE;                                                         \
    }

#define BBODY(PLANE, STORE)                                            \
    {                                                                  \
        const float* plane = (PLANE);                                  \
        float acc = 0.0f;                                              \
        _Pragma("unroll")                                              \
        for (int fj = 0; fj < 4; fj++) {                               \
            const float* rT = plane + yi[fj]  * W;                     \
            const float* rB = plane + yi1[fj] * W;                     \
            _Pragma("unroll")                                          \
            for (int fi = 0; fi < 4; fi++) {                           \
                float samp = a00 * rT[xi[fi]] + a10 * rT[xi1[fi]]      \
                           + a01 * rB[xi[fi]] + a11 * rB[xi1[fi]];     \
                acc = fmaf(fw[fj * 4 + fi], samp, acc);                \
            }                                                          \
        }                                                              \
        STORE;                                                         \
    }

__global__ __launch_bounds__(256) void interp_f_kernel(
    const float* __restrict__ im0,   const float* __restrict__ im2,
    const float* __restrict__ ctx0,  const float* __restrict__ ctx2,
    const float* __restrict__ filt0, const float* __restrict__ filt1,
    float* __restrict__ out)
{
    int lin = blockIdx.x + F_NTILE * (blockIdx.y + F_NGRP * blockIdx.z);
    int newlin = (lin & 7) * (F_NBLK / 8) + (lin >> 3);
    int tile = newlin % F_NTILE;
    int rest = newlin / F_NTILE;
    int g = rest % F_NGRP;
    int s = rest / F_NGRP;
    int b  = tile / (F_NTX * F_NTY);
    int t2 = tile % (F_NTX * F_NTY);
    int x = (t2 % F_NTX) * F_TX + ((int)threadIdx.x % F_TX);
    int y = (t2 / F_NTX) * F_TY + ((int)threadIdx.x / F_TX);
    int pix = y * W + x;

    const float* off = out + (s ? OFS_OFF1 : OFS_OFF0) + b * 2 * HW;
    float ox = off[pix];
    float oy = off[HW + pix];
    float x2 = (float)x + ox;
    float y2 = (float)y + oy;

    bool valid = (x2 >= 0.0f) && (x2 <= (float)(W - 1)) &&
                 (y2 >= 0.0f) && (y2 <= (float)(H - 1));

    const float* imsrc  = s ? im2  : im0;
    const float* ctxsrc = s ? ctx2 : ctx0;
    float* oim  = out + (s ? OFS_REF2 : OFS_REF0) + b * 3 * HW + pix;
    float* octx = out + (s ? OFS_CTX2 : OFS_CTX0) + b * CTX * HW + pix;

    int c0 = g * F_NCH, c1 = c0 + F_NCH;
    int imEnd  = c1 < 3 ? c1 : 3;
    int ctxBeg = c0 > 3 ? c0 : 3;

    if (!valid) {
        for (int c = c0; c < imEnd; c++) oim[c * HW] = 0.0f;
        for (int c = ctxBeg; c < c1; c++)
            __builtin_nontemporal_store(0.0f, &octx[(c - 3) * HW]);
        return;
    }

    float xLf = floorf(x2), yTf = floorf(y2);
    float alpha = x2 - xLf, beta = y2 - yTf;
    int xL = (int)xLf, yT = (int)yTf;

    const float* filt = (s ? filt1 : filt0) + b * 16 * HW + pix;
    float fw[16];
    #pragma unroll
    for (int t = 0; t < 16; t++) fw[t] = filt[t * HW];

    float a00 = (1.0f - alpha) * (1.0f - beta);
    float a10 = alpha * (1.0f - beta);
    float a01 = (1.0f - alpha) * beta;
    float a11 = alpha * beta;

    bool interior = (xL >= 1) && (xL <= W - 4) && (yT >= 1) && (yT <= H - 4);

    if (interior) {
        float mw[5][5];
        #pragma unroll
        for (int r = 0; r < 5; r++) {
            #pragma unroll
            for (int c = 0; c < 5; c++) {
                float v = 0.0f;
                if (r < 4 && c < 4)   v += a00 * fw[r * 4 + c];
                if (r < 4 && c >= 1)  v += a10 * fw[r * 4 + c - 1];
                if (r >= 1 && c < 4)  v += a01 * fw[(r - 1) * 4 + c];
                if (r >= 1 && c >= 1) v += a11 * fw[(r - 1) * 4 + c - 1];
                mw[r][c] = v;
            }
        }
        int base = (yT - 1) * W + (xL - 1);
        for (int c = c0; c < imEnd; c++)
            VBODY(imsrc + (b * 3 + c) * HW, oim[c * HW] = acc)
        #pragma unroll 2
        for (int c = ctxBeg; c < c1; c++)
            VBODY(ctxsrc + (b * CTX + (c - 3)) * HW,
                  __builtin_nontemporal_store(acc, &octx[(c - 3) * HW]))
    } else {
        int xi[4], xi1[4], yi[4], yi1[4];
        #pragma unroll
        for (int f = 0; f < 4; f++) {
            int a = iclip(xL + f - 1, 0, W - 1);
            xi[f]  = a;
            xi1[f] = a + 1 > W - 1 ? W - 1 : a + 1;
            int bb = iclip(yT + f - 1, 0, H - 1);
            yi[f]  = bb;
            yi1[f] = bb + 1 > H - 1 ? H - 1 : bb + 1;
        }
        for (int c = c0; c < imEnd; c++)
            BBODY(imsrc + (b * 3 + c) * HW, oim[c * HW] = acc)
        for (int c = ctxBeg; c < c1; c++)
            BBODY(ctxsrc + (b * CTX + (c - 3)) * HW,
                  __builtin_nontemporal_store(acc, &octx[(c - 3) * HW]))
    }
}

// ---------------- launch ----------------

extern "C" void kernel_launch(void* const* d_in, const int* in_sizes, int n_in,
                              void* d_out, int out_size, void* d_ws, size_t ws_size,
                              hipStream_t stream)
{
    const float* im0    = (const float*)d_in[0];
    const float* im2    = (const float*)d_in[1];
    const float* ctx0   = (const float*)d_in[2];
    const float* ctx2   = (const float*)d_in[3];
    const float* flow01 = (const float*)d_in[4];
    const float* flow10 = (const float*)d_in[5];
    const float* dep0   = (const float*)d_in[6];
    const float* dep1   = (const float*)d_in[7];
    const float* filt0  = (const float*)d_in[8];
    const float* filt1  = (const float*)d_in[9];

    float* out = (float*)d_out;

    // ws layout: T (TSZ halfs) first, then acc4 (2*BHW*4 floats).
    size_t t_bytes    = TSZ * sizeof(_Float16);
    size_t acc4_bytes = (size_t)2 * BHW * 4 * sizeof(float);
    size_t need = t_bytes + acc4_bytes;
    bool use_t = ws_size >= need;

    _Float16* T = (_Float16*)d_ws;
    float* acc4 = use_t ? (float*)((char*)d_ws + t_bytes) : (float*)d_ws;

    hipMemsetAsync(acc4, 0, acc4_bytes, stream);

    dim3 blk(256);
    if (use_t) {
        prep_kernel<<<dim3(NTB + NSPB), blk, 0, stream>>>(
            im0, im2, ctx0, ctx2, flow01, flow10, dep0, dep1, T, acc4);
        norm_kernel<<<dim3((2 * BHW + 255) / 256), blk, 0, stream>>>(out, acc4);
        interp_t_kernel<<<dim3(NBLK2), dim3(NTHR), 0, stream>>>(T, filt0, filt1, out);
    } else {
        prep_kernel<<<dim3(NTB + NSPB), blk, 0, stream>>>(
            im0, im2, ctx0, ctx2, flow01, flow10, dep0, dep1,
            (_Float16*)d_ws, acc4);
        norm_kernel<<<dim3((2 * BHW + 255) / 256), blk, 0, stream>>>(out, acc4);
        dim3 igrid(F_NTILE, F_NGRP, 2);
        interp_f_kernel<<<igrid, blk, 0, stream>>>(
            im0, im2, ctx0, ctx2, filt0, filt1, out);
    }

    cur_kernel<<<dim3((3 * BHW + 255) / 256), blk, 0, stream>>>(out);
}

// Round 18
// 421.394 us; speedup vs baseline: 6.0855x; 1.0159x over previous
//
#include <hip/hip_runtime.h>
#include <hip/hip_fp16.h>
#include <math.h>

#define B   2
#define H   192
#define W   320
#define HW  (H * W)
#define BHW (B * HW)
#define CTX 195
#define CH  198   // 3 im + 195 ctx channels per side

// output offsets (in floats), concatenated in reference return order
#define OFS_CUR   0
#define OFS_REF0  (3 * BHW)
#define OFS_REF2  (6 * BHW)
#define OFS_CTX0  (9 * BHW)
#define OFS_CTX2  (9 * BHW + CTX * BHW)
#define OFS_OFF0  (9 * BHW + 2 * CTX * BHW)
#define OFS_OFF1  (OFS_OFF0 + 2 * BHW)

// transposed-path geometry
#define TSZ    ((size_t)2 * B * HW * CH)  // elements of T (fp16)
#define NTB    (2 * B * (HW / 64))        // 3840 transpose blocks
#define NSPB   ((2 * BHW + 255) / 256)    // 960 splat blocks
#define LDSW   199                        // transpose LDS row stride (odd)
#define NPXB   16                         // pixels per interp block
#define NTHR   256                        // interp block threads (4 waves)
#define NCHK   (HW / NPXB)                // 3840 chunks per (s,b) image
#define NBLK2  (2 * B * NCHK)             // 15360 interp blocks, div by 8

// fallback (R4) geometry
#define F_NCH   33
#define F_NGRP  6
#define F_TX    32
#define F_TY    8
#define F_NTX   (W / F_TX)
#define F_NTY   (H / F_TY)
#define F_NTILE (F_NTX * F_NTY * B)       // 480
#define F_NBLK  (F_NTILE * F_NGRP * 2)    // 5760

typedef float f4a __attribute__((ext_vector_type(4), aligned(4)));
typedef _Float16 h8 __attribute__((ext_vector_type(8), aligned(4)));
typedef _Float16 h2 __attribute__((ext_vector_type(2), aligned(4)));

__device__ __forceinline__ int iclip(int v, int lo, int hi) {
    return v < lo ? lo : (v > hi ? hi : v);
}

// ---------------- fused splat + transpose ----------------
__global__ __launch_bounds__(256) void prep_kernel(
    const float* __restrict__ im0,  const float* __restrict__ im2,
    const float* __restrict__ ctx0, const float* __restrict__ ctx2,
    const float* __restrict__ flow0, const float* __restrict__ flow1,
    const float* __restrict__ dep0,  const float* __restrict__ dep1,
    _Float16* __restrict__ T, float* __restrict__ acc4)
{
    __shared__ float lds[64 * LDSW];

    if ((int)blockIdx.x < NTB) {
        int lin   = blockIdx.x;
        int chunk = lin % (HW / 64);
        int rest  = lin / (HW / 64);
        int b = rest % B;
        int s = rest / B;
        int pix0 = chunk * 64;

        const float* im  = s ? im2  : im0;
        const float* ctx = s ? ctx2 : ctx0;

        for (int j = (int)threadIdx.x; j < CH * 64; j += 256) {
            int c = j >> 6;
            int p = j & 63;
            const float* src = (c < 3) ? im + (b * 3 + c) * HW
                                       : ctx + (b * CTX + (c - 3)) * HW;
            lds[p * LDSW + c] = src[pix0 + p];
        }
        __syncthreads();
        _Float16* Tb = T + ((size_t)((s * B + b) * HW + pix0)) * CH;
        // vectorized fp16 pair stores (4B/lane, coalesced)
        for (int j = (int)threadIdx.x; j < (CH / 2) * 64; j += 256) {
            int p  = j / (CH / 2);
            int cp = j - p * (CH / 2);
            h2 v;
            v.x = (_Float16)lds[p * LDSW + 2 * cp];
            v.y = (_Float16)lds[p * LDSW + 2 * cp + 1];
            *(h2*)(Tb + (size_t)p * CH + 2 * cp) = v;
        }
    } else {
        int tid = ((int)blockIdx.x - NTB) * 256 + (int)threadIdx.x;
        if (tid >= 2 * BHW) return;
        int s   = tid / BHW;
        int p   = tid - s * BHW;
        int b   = p / HW;
        int pix = p - b * HW;
        int y   = pix / W;
        int x   = pix - y * W;

        const float* flow = s ? flow1 : flow0;
        const float* dep  = s ? dep1  : dep0;
        float fx = flow[(b * 2 + 0) * HW + pix];
        float fy = flow[(b * 2 + 1) * HW + pix];
        float d  = dep[b * HW + pix];

        int xL = (int)floorf((float)x + fx);
        int yT = (int)floorf((float)y + fy);

        float* ab = acc4 + (size_t)(s * B + b) * HW * 4;
        float wx = -fx * d;
        float wy = -fy * d;
        #pragma unroll
        for (int dy = 0; dy < 2; dy++) {
            #pragma unroll
            for (int dx = 0; dx < 2; dx++) {
                int xi = xL + dx;
                int yi = yT + dy;
                if (xi >= 0 && xi < W && yi >= 0 && yi < H) {
                    float* q = ab + (size_t)(yi * W + xi) * 4;
                    atomicAdd(q + 0, wx);
                    atomicAdd(q + 1, wy);
                    atomicAdd(q + 2, d);
                }
            }
        }
    }
}

// norm kernel (fallback path only)
__global__ __launch_bounds__(256) void norm_kernel(
    float* __restrict__ out, const float* __restrict__ acc4)
{
    int tid = blockIdx.x * blockDim.x + threadIdx.x;
    if (tid >= 2 * BHW) return;
    int s   = tid / BHW;
    int p   = tid - s * BHW;
    int b   = p / HW;
    int pix = p - b * HW;

    const float* q = acc4 + ((size_t)(s * B + b) * HW + pix) * 4;
    float ax = q[0], ay = q[1], c = q[2];
    float* acc = out + (s ? OFS_OFF1 : OFS_OFF0) + b * 2 * HW;
    if (c > 0.0f) {
        acc[pix]      = ax / c;
        acc[HW + pix] = ay / c;
    } else {
        acc[pix]      = 0.0f;
        acc[HW + pix] = 0.0f;
    }
}

__global__ __launch_bounds__(256) void cur_kernel(float* __restrict__ out)
{
    int i = blockIdx.x * blockDim.x + threadIdx.x;
    if (i < 3 * BHW)
        out[OFS_CUR + i] = 0.5f * (out[OFS_REF0 + i] + out[OFS_REF2 + i]);
}

// ---------------- transposed-gather interp ----------------
// 16 px/block, 4 waves; reads acc4 and computes/writes off planes itself
// (norm fused); per-pixel 5x5 merged weights via tap-scatter (exact clamp
// semantics); clamped row/col offsets keep all reads in-image; h8 gathers,
// 2 px per wave-load, 8 ch per lane; pr loop not unrolled.
__global__ __launch_bounds__(NTHR) void interp_t_kernel(
    const _Float16* __restrict__ T, const float* __restrict__ acc4,
    const float* __restrict__ filt0, const float* __restrict__ filt1,
    float* __restrict__ out)
{
    __shared__ float fwl[NPXB * 17];    // [p][tap]
    __shared__ float mwl[NPXB * 25];    // [p][r*5+c] merged weights
    __shared__ float geoA[NPXB * 4];    // a00,a10,a01,a11 (0 if invalid)
    __shared__ int   geoC[NPXB * 4];    // xL, yT, bx, by (sanitized)
    __shared__ int   rofs[NPXB * 5];    // clamped row offsets (elements)
    __shared__ int   cofs[NPXB * 5];    // clamped col offsets (elements)
    __shared__ float outb[NPXB * 199];  // [p][c]

    int lin = blockIdx.x;
    int newlin = (lin & 7) * (NBLK2 / 8) + (lin >> 3);   // XCD swizzle
    int chunk = newlin % NCHK;
    int rest  = newlin / NCHK;
    int b = rest % B;
    int s = rest / B;
    int px0 = chunk * NPXB;      // 16 consecutive px within one row
    int y0  = px0 / W;
    int x0  = px0 - y0 * W;

    const float* filt = (s ? filt1 : filt0) + b * 16 * HW;
    const _Float16* Tb = T + (size_t)(s * B + b) * HW * CH;

    int t = (int)threadIdx.x;

    // zero merged weights
    for (int idx = t; idx < 25 * NPXB; idx += NTHR) mwl[idx] = 0.0f;
    // cooperative filt load (one element per thread: 16 taps x 16 px = 256)
    {
        int tap = t >> 4, p = t & 15;
        fwl[p * 17 + tap] = filt[tap * HW + px0 + p];
    }
    // per-pixel geometry: read acc4, compute off (norm fused), write off out
    if (t < NPXB) {
        int p = t;
        const float* q = acc4 + ((size_t)(s * B + b) * HW + px0 + p) * 4;
        float ax = q[0], ay = q[1], cc = q[2];
        float ox = cc > 0.0f ? ax / cc : 0.0f;
        float oy = cc > 0.0f ? ay / cc : 0.0f;
        float* offw = out + (s ? OFS_OFF1 : OFS_OFF0) + b * 2 * HW;
        offw[px0 + p]      = ox;
        offw[HW + px0 + p] = oy;

        float x2 = (float)(x0 + p) + ox;
        float y2 = (float)y0 + oy;
        bool valid = (x2 >= 0.0f) && (x2 <= (float)(W - 1)) &&
                     (y2 >= 0.0f) && (y2 <= (float)(H - 1));
        float xLf = floorf(x2), yTf = floorf(y2);
        float al = x2 - xLf, be = y2 - yTf;
        int xL = valid ? (int)xLf : 1;
        int yT = valid ? (int)yTf : 1;
        geoA[p * 4 + 0] = valid ? (1.0f - al) * (1.0f - be) : 0.0f;
        geoA[p * 4 + 1] = valid ? al * (1.0f - be) : 0.0f;
        geoA[p * 4 + 2] = valid ? (1.0f - al) * be : 0.0f;
        geoA[p * 4 + 3] = valid ? al * be : 0.0f;
        geoC[p * 4 + 0] = xL;
        geoC[p * 4 + 1] = yT;
        geoC[p * 4 + 2] = xL - 1 > 0 ? xL - 1 : 0;   // bx
        geoC[p * 4 + 3] = yT - 1 > 0 ? yT - 1 : 0;   // by
    }
    __syncthreads();

    // clamped row/col element offsets (weight-nonzero cells never clamp)
    if (t < 2 * 5 * NPXB) {
        if (t < 5 * NPXB) {
            int p = t / 5, r = t - p * 5;
            int by = geoC[p * 4 + 3];
            int yr = by + r; if (yr > H - 1) yr = H - 1;
            rofs[p * 5 + r] = yr * (W * CH);
        } else {
            int j = t - 5 * NPXB;
            int p = j / 5, c = j - p * 5;
            int bx = geoC[p * 4 + 2];
            int xc = bx + c; if (xc > W - 1) xc = W - 1;
            cofs[p * 5 + c] = xc * CH;
        }
    }

    // tap-scatter: one thread per (pixel, tap); exact per-corner clamping
    {
        int p = t >> 4, tap = t & 15;
        int fi = tap & 3, fj = tap >> 2;
        int xL = geoC[p * 4 + 0], yT = geoC[p * 4 + 1];
        int bx = geoC[p * 4 + 2], by = geoC[p * 4 + 3];
        float fw = fwl[p * 17 + tap];
        float a00 = geoA[p * 4 + 0], a10 = geoA[p * 4 + 1];
        float a01 = geoA[p * 4 + 2], a11 = geoA[p * 4 + 3];
        int xi  = iclip(xL + fi - 1, 0, W - 1);
        int xi1 = xi + 1 > W - 1 ? W - 1 : xi + 1;
        int yi  = iclip(yT + fj - 1, 0, H - 1);
        int yi1 = yi + 1 > H - 1 ? H - 1 : yi + 1;
        float* mwp = &mwl[p * 25];
        atomicAdd(&mwp[(yi  - by) * 5 + (xi  - bx)], fw * a00);
        atomicAdd(&mwp[(yi  - by) * 5 + (xi1 - bx)], fw * a10);
        atomicAdd(&mwp[(yi1 - by) * 5 + (xi  - bx)], fw * a01);
        atomicAdd(&mwp[(yi1 - by) * 5 + (xi1 - bx)], fw * a11);
    }
    __syncthreads();

    // branch-free gather: 2 pixels per wave-load, 8 ch per lane.
    int wave = t >> 6, lane = t & 63;    // wave in [0,4)
    int grp = lane >> 5;                 // 0: px A, 1: px B
    int li  = lane & 31;
    int lcl = li < 24 ? li : 24;
    int ch0 = lcl * 8;                   // channels ch0..ch0+7 (lane 24: 6 valid)

    #pragma unroll 1
    for (int pr = 0; pr < 2; pr++) {
        int p = wave * 4 + pr * 2 + grp; // 4 waves x 4 px = 16 px
        const float* mwp = &mwl[p * 25];
        const int* rp = &rofs[p * 5];
        const int* cp = &cofs[p * 5];
        const _Float16* bp = Tb + ch0;
        float a0 = 0, a1 = 0, a2 = 0, a3 = 0, a4 = 0, a5 = 0, a6 = 0, a7 = 0;
        #pragma unroll
        for (int r = 0; r < 5; r++) {
            const _Float16* rowp = bp + rp[r];
            #pragma unroll
            for (int c = 0; c < 5; c++) {
                h8 v = *(const h8*)(rowp + cp[c]);
                float w = mwp[r * 5 + c];
                a0 = fmaf(w, (float)v[0], a0);
                a1 = fmaf(w, (float)v[1], a1);
                a2 = fmaf(w, (float)v[2], a2);
                a3 = fmaf(w, (float)v[3], a3);
                a4 = fmaf(w, (float)v[4], a4);
                a5 = fmaf(w, (float)v[5], a5);
                a6 = fmaf(w, (float)v[6], a6);
                a7 = fmaf(w, (float)v[7], a7);
            }
        }
        float* ob = &outb[p * 199 + ch0];
        if (li < 24) {
            ob[0] = a0; ob[1] = a1; ob[2] = a2; ob[3] = a3;
            ob[4] = a4; ob[5] = a5; ob[6] = a6; ob[7] = a7;
        } else if (li == 24) {
            ob[0] = a0; ob[1] = a1; ob[2] = a2;
            ob[3] = a3; ob[4] = a4; ob[5] = a5;
        }
    }

    __syncthreads();
    // coalesced plane writes
    for (int idx = t; idx < CH * NPXB; idx += NTHR) {
        int c = idx >> 4;
        int p = idx & 15;
        float v = outb[p * 199 + c];
        if (c < 3)
            out[(s ? OFS_REF2 : OFS_REF0) + (b * 3 + c) * HW + px0 + p] = v;
        else
            __builtin_nontemporal_store(
                v, &out[(s ? OFS_CTX2 : OFS_CTX0) + (b * CTX + (c - 3)) * HW + px0 + p]);
    }
}

// ---------------- fallback path (R4 interp, fp32 planes) ----------------

#define VBODY(PLANE, STORE)                                            \
    {                                                                  \
        const float* p0 = (PLANE) + base;                              \
        float acc = 0.0f;                                              \
        _Pragma("unroll")                                              \
        for (int r = 0; r < 5; r++) {                                  \
            const float* row = p0 + r * W;                             \
            f4a v0 = *(const f4a*)row;                                 \
            float v4 = row[4];                                         \
            acc = fmaf(mw[r][0], v0.x, acc);                           \
            acc = fmaf(mw[r][1], v0.y, acc);                           \
            acc = fmaf(mw[r][2], v0.z, acc);                           \
            acc = fmaf(mw[r][3], v0.w, acc);                           \
            acc = fmaf(mw[r][4], v4,   acc);                           \
        }                                                              \
        STORE;                                                         \
    }

#define BBODY(PLANE, STORE)                                            \
    {                                                                  \
        const float* plane = (PLANE);                                  \
        float acc = 0.0f;                                              \
        _Pragma("unroll")                                              \
        for (int fj = 0; fj < 4; fj++) {                               \
            const float* rT = plane + yi[fj]  * W;                     \
            const float* rB = plane + yi1[fj] * W;                     \
            _Pragma("unroll")                                          \
            for (int fi = 0; fi < 4; fi++) {                           \
                float samp = a00 * rT[xi[fi]] + a10 * rT[xi1[fi]]      \
                           + a01 * rB[xi[fi]] + a11 * rB[xi1[fi]];     \
                acc = fmaf(fw[fj * 4 + fi], samp, acc);                \
            }                                                          \
        }                                                              \
        STORE;                                                         \
    }

__global__ __launch_bounds__(256) void interp_f_kernel(
    const float* __restrict__ im0,   const float* __restrict__ im2,
    const float* __restrict__ ctx0,  const float* __restrict__ ctx2,
    const float* __restrict__ filt0, const float* __restrict__ filt1,
    float* __restrict__ out)
{
    int lin = blockIdx.x + F_NTILE * (blockIdx.y + F_NGRP * blockIdx.z);
    int newlin = (lin & 7) * (F_NBLK / 8) + (lin >> 3);
    int tile = newlin % F_NTILE;
    int rest = newlin / F_NTILE;
    int g = rest % F_NGRP;
    int s = rest / F_NGRP;
    int b  = tile / (F_NTX * F_NTY);
    int t2 = tile % (F_NTX * F_NTY);
    int x = (t2 % F_NTX) * F_TX + ((int)threadIdx.x % F_TX);
    int y = (t2 / F_NTX) * F_TY + ((int)threadIdx.x / F_TX);
    int pix = y * W + x;

    const float* off = out + (s ? OFS_OFF1 : OFS_OFF0) + b * 2 * HW;
    float ox = off[pix];
    float oy = off[HW + pix];
    float x2 = (float)x + ox;
    float y2 = (float)y + oy;

    bool valid = (x2 >= 0.0f) && (x2 <= (float)(W - 1)) &&
                 (y2 >= 0.0f) && (y2 <= (float)(H - 1));

    const float* imsrc  = s ? im2  : im0;
    const float* ctxsrc = s ? ctx2 : ctx0;
    float* oim  = out + (s ? OFS_REF2 : OFS_REF0) + b * 3 * HW + pix;
    float* octx = out + (s ? OFS_CTX2 : OFS_CTX0) + b * CTX * HW + pix;

    int c0 = g * F_NCH, c1 = c0 + F_NCH;
    int imEnd  = c1 < 3 ? c1 : 3;
    int ctxBeg = c0 > 3 ? c0 : 3;

    if (!valid) {
        for (int c = c0; c < imEnd; c++) oim[c * HW] = 0.0f;
        for (int c = ctxBeg; c < c1; c++)
            __builtin_nontemporal_store(0.0f, &octx[(c - 3) * HW]);
        return;
    }

    float xLf = floorf(x2), yTf = floorf(y2);
    float alpha = x2 - xLf, beta = y2 - yTf;
    int xL = (int)xLf, yT = (int)yTf;

    const float* filt = (s ? filt1 : filt0) + b * 16 * HW + pix;
    float fw[16];
    #pragma unroll
    for (int t = 0; t < 16; t++) fw[t] = filt[t * HW];

    float a00 = (1.0f - alpha) * (1.0f - beta);
    float a10 = alpha * (1.0f - beta);
    float a01 = (1.0f - alpha) * beta;
    float a11 = alpha * beta;

    bool interior = (xL >= 1) && (xL <= W - 4) && (yT >= 1) && (yT <= H - 4);

    if (interior) {
        float mw[5][5];
        #pragma unroll
        for (int r = 0; r < 5; r++) {
            #pragma unroll
            for (int c = 0; c < 5; c++) {
                float v = 0.0f;
                if (r < 4 && c < 4)   v += a00 * fw[r * 4 + c];
                if (r < 4 && c >= 1)  v += a10 * fw[r * 4 + c - 1];
                if (r >= 1 && c < 4)  v += a01 * fw[(r - 1) * 4 + c];
                if (r >= 1 && c >= 1) v += a11 * fw[(r - 1) * 4 + c - 1];
                mw[r][c] = v;
            }
        }
        int base = (yT - 1) * W + (xL - 1);
        for (int c = c0; c < imEnd; c++)
            VBODY(imsrc + (b * 3 + c) * HW, oim[c * HW] = acc)
        #pragma unroll 2
        for (int c = ctxBeg; c < c1; c++)
            VBODY(ctxsrc + (b * CTX + (c - 3)) * HW,
                  __builtin_nontemporal_store(acc, &octx[(c - 3) * HW]))
    } else {
        int xi[4], xi1[4], yi[4], yi1[4];
        #pragma unroll
        for (int f = 0; f < 4; f++) {
            int a = iclip(xL + f - 1, 0, W - 1);
            xi[f]  = a;
            xi1[f] = a + 1 > W - 1 ? W - 1 : a + 1;
            int bb = iclip(yT + f - 1, 0, H - 1);
            yi[f]  = bb;
            yi1[f] = bb + 1 > H - 1 ? H - 1 : bb + 1;
        }
        for (int c = c0; c < imEnd; c++)
            BBODY(imsrc + (b * 3 + c) * HW, oim[c * HW] = acc)
        for (int c = ctxBeg; c < c1; c++)
            BBODY(ctxsrc + (b * CTX + (c - 3)) * HW,
                  __builtin_nontemporal_store(acc, &octx[(c - 3) * HW]))
    }
}

// ---------------- launch ----------------

extern "C" void kernel_launch(void* const* d_in, const int* in_sizes, int n_in,
                              void* d_out, int out_size, void* d_ws, size_t ws_size,
                              hipStream_t stream)
{
    const float* im0    = (const float*)d_in[0];
    const float* im2    = (const float*)d_in[1];
    const float* ctx0   = (const float*)d_in[2];
    const float* ctx2   = (const float*)d_in[3];
    const float* flow01 = (const float*)d_in[4];
    const float* flow10 = (const float*)d_in[5];
    const float* dep0   = (const float*)d_in[6];
    const float* dep1   = (const float*)d_in[7];
    const float* filt0  = (const float*)d_in[8];
    const float* filt1  = (const float*)d_in[9];

    float* out = (float*)d_out;

    // ws layout: T (TSZ halfs) first, then acc4 (2*BHW*4 floats).
    size_t t_bytes    = TSZ * sizeof(_Float16);
    size_t acc4_bytes = (size_t)2 * BHW * 4 * sizeof(float);
    size_t need = t_bytes + acc4_bytes;
    bool use_t = ws_size >= need;

    _Float16* T = (_Float16*)d_ws;
    float* acc4 = use_t ? (float*)((char*)d_ws + t_bytes) : (float*)d_ws;

    hipMemsetAsync(acc4, 0, acc4_bytes, stream);

    dim3 blk(256);
    if (use_t) {
        prep_kernel<<<dim3(NTB + NSPB), blk, 0, stream>>>(
            im0, im2, ctx0, ctx2, flow01, flow10, dep0, dep1, T, acc4);
        interp_t_kernel<<<dim3(NBLK2), dim3(NTHR), 0, stream>>>(
            T, acc4, filt0, filt1, out);
    } else {
        prep_kernel<<<dim3(NTB + NSPB), blk, 0, stream>>>(
            im0, im2, ctx0, ctx2, flow01, flow10, dep0, dep1,
            (_Float16*)d_ws, acc4);
        norm_kernel<<<dim3((2 * BHW + 255) / 256), blk, 0, stream>>>(out, acc4);
        dim3 igrid(F_NTILE, F_NGRP, 2);
        interp_f_kernel<<<igrid, blk, 0, stream>>>(
            im0, im2, ctx0, ctx2, filt0, filt1, out);
    }

    cur_kernel<<<dim3((3 * BHW + 255) / 256), blk, 0, stream>>>(out);
}